// Round 7
// baseline (91.682 us; speedup 1.0000x reference)
//
#include <hip/hip_runtime.h>
#include <math.h>

// Problem constants (reference: K=256, Q=64, T=500001 -> n = 500000)
// KEY ALGEBRA (verified R4/R5, absmax 0.0): all relu inputs are > 0
// (softplus weights, squared residuals, nonneg var), so relu is identity and
// the K=256 MLP collapses to a sliding 64-dot:
//   sigma2(t) = c0 + sum_{e=0}^{63} u2_full[t+e] * vr[e]
//   vr[e] = sum_k softplus(raw_beta)[k] * softplus(raw_w)[k][63-e]
//   c0    = softplus(raw_beta0) + sum_k beta_k*softplus(raw_w0)[k] + 1e-8
//
// R5 post-mortem: kernel BODIES don't move the total; DISPATCH COUNT does
// (R0->R2: -1 dispatch = -11.6us; R2->R5: -6us of body = 0). So: 2 dispatches.
// The only global dependency is var(u2) -> u2_full[0..63] -> affects ONLY the
// 64 terms t<64. k_main blocks are self-sufficient (local u2 window from r,
// redundant per-block vr contraction); block 0 defers its t<64 terms by
// emitting sg_partial(t) (zeros in the var slots) + vr; k_final computes var
// from per-block moments and patches sigma2 = sg_partial + var*csum(t).
// NO fences, NO grid sync (R1 lesson: __threadfence = agent-scope on gfx950,
// per-block L2 writeback, catastrophic).
// R6: container-level infra failure (no test verdict); resubmitted with vrs
// hardened to __align__(16) for the f32x4 LDS reads — only change.
#define K_ 256
#define Q_ 64
#define NT 500000
#define TPB 2048                              // t per k_main block (8/thread)
#define GRID_MAIN ((NT + TPB - 1) / TPB)      // 245

// Workspace layout (float offsets) — tiny now:
#define WS_PART  0                            // [245] per-block sum(u2)
#define WS_PART2 (WS_PART + 256)              // [245] per-block sum(u2^2)
#define WS_OUT   (WS_PART2 + 256)             // [245] per-block NLL partials (t>=64)
#define WS_SG64  (WS_OUT + 256)               // [64] block0 var-independent sigma2(t), t<64
#define WS_U264  (WS_SG64 + 64)               // [64] u2[t], t<64
#define WS_VR    (WS_U264 + 64)               // [64] vr[e] (window order)

typedef __attribute__((ext_vector_type(4))) float f32x4;

__device__ __forceinline__ float softplusf(float x) {
    return (x > 20.f) ? x : log1pf(__expf(x));
}

// Kernel A: everything except the var-dependent 64 terms and the final sum.
// Each block: (1) softplus(beta) -> LDS; (2) 16 independent f32x4 loads of
// raw_w per thread (R4 lesson: keep the latency chain 1-deep, not 64-deep);
// (3) local u2 window [t0-64, t0+2048) from r into LDS (+ moment partials);
// (4) contraction FMAs -> vr; (5) rolling-register sliding 64-dot; (6) NLL
// partial for its t-range (block 0: t>=64 only, t<64 deferred).
__launch_bounds__(256)
__global__ void k_main(const float* __restrict__ r,
                       const float* __restrict__ a0p,
                       const float* __restrict__ a1p,
                       const float* __restrict__ rb0,
                       const float* __restrict__ rbeta,
                       const float* __restrict__ rw0,
                       const float* __restrict__ rw,
                       float* __restrict__ ws) {
    __shared__ __align__(16) float su[TPB + Q_];    // 2112 floats
    __shared__ float sbeta[K_];
    __shared__ __align__(16) f32x4 vpart[16][16];   // [k-chunk][j-quad]
    __shared__ __align__(16) float vrs[Q_];         // window-order weights
    __shared__ float sc0s;
    __shared__ float red[4][3];
    int tid = threadIdx.x;
    int l = tid & 63, w = tid >> 6;
    float a0 = a0p[0], a1 = a1p[0];
    int t0 = blockIdx.x * TPB;
    int base = t0 - Q_;                             // j-index of su[0]

    // (1) beta softplus (one per thread)
    sbeta[tid] = softplusf(rbeta[tid]);

    // (2) contraction loads: thread (c,jq) = 16 INDEPENDENT f32x4 loads
    int c = tid >> 4, jq = tid & 15;
    f32x4 wv[16];
    #pragma unroll
    for (int kk = 0; kk < 16; ++kk)
        wv[kk] = *(const f32x4*)(rw + (16 * c + kk) * Q_ + 4 * jq);

    // (3) u2 window -> LDS (zeros for j<0 [var slots] and j>=NT) + moments.
    //     Moments count only m>=64 (j in [t0,t0+2048)): each j once globally.
    float v = 0.f, v2 = 0.f;
    for (int qd = tid; qd < (TPB + Q_) / 4; qd += 256) {
        int m = 4 * qd;
        int j = base + m;
        f32x4 qv;
        if (j >= 0 && j + 8 <= NT + 1) {            // full-vector path
            f32x4 ra = *(const f32x4*)(r + j);
            f32x4 rb = *(const f32x4*)(r + j + 4);
            float u0 = ra[1] - a0 - a1 * ra[0];
            float u1 = ra[2] - a0 - a1 * ra[1];
            float u2 = ra[3] - a0 - a1 * ra[2];
            float u3 = rb[0] - a0 - a1 * ra[3];
            qv[0] = u0*u0; qv[1] = u1*u1; qv[2] = u2*u2; qv[3] = u3*u3;
        } else {                                    // edges: scalar + guards
            #pragma unroll
            for (int d = 0; d < 4; ++d) {
                int je = j + d;
                float q = 0.f;
                if (je >= 0 && je < NT) {
                    float u = r[je + 1] - a0 - a1 * r[je];
                    q = u * u;
                }
                qv[d] = q;
            }
        }
        *(f32x4*)(su + m) = qv;
        if (m >= Q_) {                              // OOB slots are 0: add 0
            v  += (qv[0] + qv[1]) + (qv[2] + qv[3]);
            v2 += (qv[0]*qv[0] + qv[1]*qv[1]) + (qv[2]*qv[2] + qv[3]*qv[3]);
        }
    }
    __syncthreads();

    // (4) contraction FMAs (sbeta from LDS) + c0 partial
    f32x4 pv; pv[0] = pv[1] = pv[2] = pv[3] = 0.f;
    #pragma unroll
    for (int kk = 0; kk < 16; ++kk) {
        float bk = sbeta[16 * c + kk];
        pv[0] = fmaf(bk, softplusf(wv[kk][0]), pv[0]);
        pv[1] = fmaf(bk, softplusf(wv[kk][1]), pv[1]);
        pv[2] = fmaf(bk, softplusf(wv[kk][2]), pv[2]);
        pv[3] = fmaf(bk, softplusf(wv[kk][3]), pv[3]);
    }
    vpart[c][jq] = pv;
    float pc = sbeta[tid] * softplusf(rw0[tid]);
    #pragma unroll
    for (int mask = 1; mask < 64; mask <<= 1)
        pc += __shfl_xor(pc, mask, 64);
    if (l == 0) red[w][0] = pc;
    __syncthreads();

    // (5) combine vr (REVERSED into window order: vrs[e] = v[63-e]) + c0
    if (tid < Q_) {
        int qq = tid >> 2, dd = tid & 3;
        float vj = 0.f;
        #pragma unroll
        for (int cc = 0; cc < 16; ++cc) vj += vpart[cc][qq][dd];
        vrs[Q_ - 1 - tid] = vj;
        if (blockIdx.x == 0) ws[WS_VR + (Q_ - 1 - tid)] = vj;  // for k_final csum
    }
    if (tid == 0)
        sc0s = softplusf(rb0[0])
             + ((red[0][0] + red[1][0]) + (red[2][0] + red[3][0])) + 1e-8f;
    __syncthreads();

    // (6) sliding 64-dot: thread owns t = t0+8*tid+{0..7}; window
    //     su[8*tid .. 8*tid+71]; rolling A,B,C f32x4s, all indices static.
    float c0v = sc0s;
    float acc[8];
    #pragma unroll
    for (int jj = 0; jj < 8; ++jj) acc[jj] = c0v;
    f32x4 vr4[16];
    #pragma unroll
    for (int mc = 0; mc < 16; ++mc)
        vr4[mc] = *(const f32x4*)(vrs + 4 * mc);    // broadcast reads
    const float* sw = su + 8 * tid;
    f32x4 A = *(const f32x4*)(sw);
    f32x4 B = *(const f32x4*)(sw + 4);
    #pragma unroll
    for (int mc = 0; mc < 16; ++mc) {
        f32x4 C = *(const f32x4*)(sw + 4 * mc + 8);
        #pragma unroll
        for (int d = 0; d < 4; ++d) {
            float vv = vr4[mc][d];
            #pragma unroll
            for (int jj = 0; jj < 8; ++jj) {
                int idx = d + jj;                   // 0..10, compile-time
                float x = idx < 4 ? A[idx] : (idx < 8 ? B[idx - 4] : C[idx - 8]);
                acc[jj] = fmaf(x, vv, acc[jj]);
            }
        }
        A = B; B = C;
    }

    // (7) NLL partial (t in [64,NT) only; block0's t<64 deferred to k_final)
    float val = 0.f;
    int tb = t0 + 8 * tid;
    #pragma unroll
    for (int jj = 0; jj < 8; ++jj) {
        int t = tb + jj;
        float sg = acc[jj];
        if (t >= Q_ && t < NT) {
            float u2t = su[8 * tid + jj + Q_];      // = u2[t], bitwise
            val += __logf(sg) + u2t / sg;
        }
    }
    if (blockIdx.x == 0 && tid < 8) {
        #pragma unroll
        for (int jj = 0; jj < 8; ++jj) {
            int t = 8 * tid + jj;                   // 0..63
            ws[WS_SG64 + t] = acc[jj];              // var slots were 0 in su
            ws[WS_U264 + t] = su[8 * tid + jj + Q_];
        }
    }

    // (8) triple reduction -> per-block scalars (plain stores, no atomics)
    #pragma unroll
    for (int mask = 1; mask < 64; mask <<= 1) {
        v   += __shfl_xor(v,   mask, 64);
        v2  += __shfl_xor(v2,  mask, 64);
        val += __shfl_xor(val, mask, 64);
    }
    if (l == 0) { red[w][0] = v; red[w][1] = v2; red[w][2] = val; }
    __syncthreads();
    if (tid == 0) {
        ws[WS_PART  + blockIdx.x] = (red[0][0] + red[1][0]) + (red[2][0] + red[3][0]);
        ws[WS_PART2 + blockIdx.x] = (red[0][1] + red[1][1]) + (red[2][1] + red[3][1]);
        ws[WS_OUT   + blockIdx.x] = (red[0][2] + red[1][2]) + (red[2][2] + red[3][2]);
    }
}

// Kernel B: var from the 245 moment pairs; patch the 64 deferred terms
// (sigma2 = sg_partial + var*csum(t), csum(t) = sum_{e<64-t} vr[e]); sum all.
__global__ void k_final(const float* __restrict__ ws, float* __restrict__ out) {
    __shared__ float svr[Q_];
    __shared__ float r1[4], r2[4], red[4];
    int tid = threadIdx.x;
    int l = tid & 63, w = tid >> 6;

    float s1 = (tid < GRID_MAIN) ? ws[WS_PART  + tid] : 0.f;
    float s2 = (tid < GRID_MAIN) ? ws[WS_PART2 + tid] : 0.f;
    float so = (tid < GRID_MAIN) ? ws[WS_OUT   + tid] : 0.f;
    if (tid < Q_) svr[tid] = ws[WS_VR + tid];

    #pragma unroll
    for (int mask = 1; mask < 64; mask <<= 1) {
        s1 += __shfl_xor(s1, mask, 64);
        s2 += __shfl_xor(s2, mask, 64);
    }
    if (l == 0) { r1[w] = s1; r2[w] = s2; }
    __syncthreads();
    float S1 = (r1[0] + r1[1]) + (r1[2] + r1[3]);
    float S2 = (r2[0] + r2[1]) + (r2[2] + r2[3]);
    float n = (float)NT;
    float var = (S2 - S1 * S1 / n) / (n - 1.f);

    float val = 0.f;
    if (tid < Q_) {                                 // deferred t = tid
        float cs = 0.f;
        for (int e = 0; e < Q_ - tid; ++e) cs += svr[e];
        float sg = ws[WS_SG64 + tid] + var * cs;
        val = __logf(sg) + ws[WS_U264 + tid] / sg;
    }
    float tot = so + val;
    #pragma unroll
    for (int mask = 1; mask < 64; mask <<= 1)
        tot += __shfl_xor(tot, mask, 64);
    if (l == 0) red[w] = tot;
    __syncthreads();
    if (tid == 0)
        out[0] = 0.5f * (float)NT * 1.8378770664093453f
               + 0.5f * ((red[0] + red[1]) + (red[2] + red[3]));
}

extern "C" void kernel_launch(void* const* d_in, const int* in_sizes, int n_in,
                              void* d_out, int out_size, void* d_ws, size_t ws_size,
                              hipStream_t stream) {
    const float* r        = (const float*)d_in[0];
    const float* a0       = (const float*)d_in[1];
    const float* a1       = (const float*)d_in[2];
    const float* raw_b0   = (const float*)d_in[3];
    const float* raw_beta = (const float*)d_in[4];
    const float* raw_w0   = (const float*)d_in[5];
    const float* raw_w    = (const float*)d_in[6];
    float* out = (float*)d_out;
    float* ws  = (float*)d_ws;

    k_main<<<GRID_MAIN, 256, 0, stream>>>(
        r, a0, a1, raw_b0, raw_beta, raw_w0, raw_w, ws);

    k_final<<<1, 256, 0, stream>>>(ws, out);
}